// Round 12
// baseline (186.037 us; speedup 1.0000x reference)
//
#include <hip/hip_runtime.h>
#include <hip/hip_bf16.h>

#define NEG 0.2f

typedef short bf16x8 __attribute__((ext_vector_type(8)));
typedef float floatx4 __attribute__((ext_vector_type(4)));

__device__ __forceinline__ float leaky(float v) { return v > 0.f ? v : NEG * v; }

__device__ __forceinline__ void unpack2(unsigned w, float& lo, float& hi) {
    union { unsigned u; float f; } a, b;
    a.u = w << 16;
    b.u = w & 0xffff0000u;
    lo = a.f; hi = b.f;
}

__device__ __forceinline__ unsigned short f2bf(float f) {
    union { float f; unsigned u; } v; v.f = f;
    unsigned r = v.u + 0x7fff + ((v.u >> 16) & 1);
    return (unsigned short)(r >> 16);
}

// ---------------- prelude: logits + x->bf16 + ELL edge fill + W packs ------
__global__ void prelude(const float* __restrict__ x, const float* __restrict__ W1,
                        const float* __restrict__ as1, const float* __restrict__ ad1,
                        const float* __restrict__ W2, const float* __restrict__ Wg,
                        const int* __restrict__ ei,
                        unsigned* __restrict__ xbu,          // [n][16] packed bf16x2
                        float* __restrict__ als1, float* __restrict__ ald1,
                        unsigned short* __restrict__ W2p,
                        unsigned short* __restrict__ W1p,
                        unsigned short* __restrict__ Wgp,
                        int* __restrict__ deg, int* __restrict__ col64,
                        int n, int E, int nTB, int nFB) {
    __shared__ float xr[64][36];      // stride 36: 16B-aligned float4 rows
    __shared__ float WaS[128];        // [j*4+h] = sum_c W1[j][h*64+c]*a_src[h][c]
    __shared__ float WaD[128];
    int b = blockIdx.x;
    int t = threadIdx.x;

    if (b >= nTB) {
        int fb = b - nTB;
        if (fb < nFB) {
            int i = fb * 256 + t;
            int tot = E + n;
            if (i < tot) {
                int src, dst;
                if (i < E) { src = ei[i]; dst = ei[E + i]; }
                else { src = i - E; dst = i - E; }
                int slot = atomicAdd(&deg[dst], 1);
                if (slot < 64) col64[(size_t)dst * 64 + slot] = src;
            }
        } else {
            // pack W2 [256,64] -> bf16 MFMA B fragments (K=32 tiles x 8)
            for (int idx = t; idx < 32 * 64; idx += 256) {
                int frag = idx >> 6, lane = idx & 63;
                int ct = frag >> 3, kt = frag & 7;
                int nn = ct * 16 + (lane & 15);
                int kb = kt * 32 + (lane >> 4) * 8;
#pragma unroll
                for (int j = 0; j < 8; j++)
                    W2p[frag * 512 + lane * 8 + j] = f2bf(W2[(kb + j) * 64 + nn]);
            }
            // pack W1 [32,256] -> per-head B fragments: frag = h*4+nt
            for (int idx = t; idx < 16 * 512; idx += 256) {
                int frag = idx >> 9;
                int h = frag >> 2, nt = frag & 3;
                int pos = idx & 511;
                int lane = pos >> 3, j = pos & 7;
                int coln = lane & 15, quad = lane >> 4;
                int k = quad * 8 + j;
                W1p[idx] = f2bf(W1[k * 256 + h * 64 + nt * 16 + coln]);
            }
            // pack Wg [64,32] -> B fragments: frag = nt*2+kt (nt,kt in 0..1)
            for (int idx = t; idx < 4 * 512; idx += 256) {
                int frag = idx >> 9;
                int nt = frag >> 1, kt = frag & 1;
                int pos = idx & 511;
                int lane = pos >> 3, j = pos & 7;
                int coln = lane & 15, quad = lane >> 4;
                int k = kt * 32 + quad * 8 + j;
                Wgp[idx] = f2bf(Wg[k * 32 + nt * 16 + coln]);
            }
        }
        return;
    }

    // ---- 64 nodes: stage x, rank-1 logit tables, logits, xb bf16 ----
    int base = b * 64;
    for (int rep = 0; rep < 2; rep++) {
        int s = t + 256 * rep;            // float4 slot 0..511
        int node = s >> 3, quad = s & 7;
        float4 v = make_float4(0.f, 0.f, 0.f, 0.f);
        if (base + node < n) v = ((const float4*)(x + (size_t)base * 32))[s];
        *((float4*)(&xr[node][quad * 4])) = v;
    }
    {
        int j = (t & 127) >> 2, h = t & 3;
        const float* av = (t < 128) ? as1 : ad1;
        float s_ = 0.f;
#pragma unroll 8
        for (int c = 0; c < 64; c++) s_ += W1[j * 256 + h * 64 + c] * av[h * 64 + c];
        if (t < 128) WaS[t] = s_; else WaD[t - 128] = s_;
    }
    __syncthreads();

    // logits: 64 nodes x 4 heads x {src,dst} = 512 32-dots
    for (int rep = 0; rep < 2; rep++) {
        int q = t + 256 * rep;
        int node = q >> 3, r = q & 7, h = r >> 1, sd = r & 1;
        int gnode = base + node;
        if (gnode < n) {
            const float* cf = sd ? WaD : WaS;
            float d_ = 0.f;
#pragma unroll
            for (int j = 0; j < 32; j++) d_ += xr[node][j] * cf[j * 4 + h];
            if (sd == 0) als1[(size_t)gnode * 4 + h] = d_;
            else         ald1[(size_t)gnode * 4 + h] = d_;
        }
    }
    // xb: bf16 x rows (the gather target - 1.25 MB, L2-resident)
    for (int rep = 0; rep < 4; rep++) {
        int i = t + 256 * rep;            // 0..1023 = 64 nodes x 16 pairs
        int node = i >> 4, cp = i & 15;
        int gnode = base + node;
        if (gnode < n) {
            unsigned short u0 = f2bf(xr[node][cp * 2]);
            unsigned short u1 = f2bf(xr[node][cp * 2 + 1]);
            xbu[(size_t)gnode * 16 + cp] = ((unsigned)u1 << 16) | u0;
        }
    }
}

// ---------------- FUSED: GAT1 x-space aggregate + W1 MFMA + W2 MFMA --------
// Phase 1 lane layout = (e4 = lane>>4, cp = lane&15): each 16-lane group
// fetches a DIFFERENT edge's 64B xbu row (4 lines = 256B per VMEM instr,
// 4x fewer load instructions than the broadcast layout); every lane carries
// all 4 heads' accumulators as floatx4. Cross-group xor(16,32) tree + a
// compile-time component select replace the old zero-shuffle epilogue.
__global__ __launch_bounds__(512) void gat1_agg_mfma(
        const unsigned* __restrict__ xbu,
        const float* __restrict__ als1, const float* __restrict__ ald1,
        const int* __restrict__ deg, const int* __restrict__ col64,
        const float* __restrict__ b1,
        const unsigned short* __restrict__ W1p,
        const unsigned short* __restrict__ W2p,
        const float* __restrict__ asr, const float* __restrict__ adt,
        __hip_bfloat16* __restrict__ h2b,
        float* __restrict__ als, float* __restrict__ ald,
        float* __restrict__ dinv, int n) {
    __shared__ unsigned short xs[16 * 264];
    __shared__ unsigned short agx[16 * 136];   // [node][h*32+ch] bf16
    __shared__ float aps[4][16];
    __shared__ float apd[4][16];
    __shared__ float4 ewL4[1024];              // 16 KB: per-edge-slot head weights
    __shared__ int    colL[1024];              // 4 KB: per-edge-slot sources
    int t = threadIdx.x;              // 512 = 8 waves
    int w = t >> 6, lane = t & 63;
    int base = blockIdx.x * 16;

    // ---- phase 0: cooperative edge staging (1024 slots, 2 per thread) ----
    for (int rep = 0; rep < 2; rep++) {
        int idx = t + 512 * rep;               // 0..1023
        int r = idx >> 6, e = idx & 63;
        int dst = base + r;
        int s = 0;
        float4 w4 = make_float4(0.f, 0.f, 0.f, 0.f);
        if (dst < n) {
            int dgf = deg[dst];
            int dg = dgf < 64 ? dgf : 64;
            if (e < dg) {
                s = col64[(size_t)dst * 64 + e];
                float4 as4 = ((const float4*)als1)[s];
                float4 ad4 = ((const float4*)ald1)[dst];
                w4.x = __expf(leaky(as4.x + ad4.x));
                w4.y = __expf(leaky(as4.y + ad4.y));
                w4.z = __expf(leaky(as4.z + ad4.z));
                w4.w = __expf(leaky(as4.w + ad4.w));
            }
        }
        colL[idx] = s;
        ewL4[idx] = w4;
    }
    __syncthreads();

    // ---- phase 1: x-space aggregation, 2 dsts per wave, 4 edges/instr ----
    {
        int e4 = lane >> 4, cp = lane & 15;
        for (int rep = 0; rep < 2; rep++) {
            int r = w * 2 + rep;
            int dst = base + r;
            floatx4 acc0 = {0.f, 0.f, 0.f, 0.f};
            floatx4 acc1 = {0.f, 0.f, 0.f, 0.f};
            floatx4 wsv  = {0.f, 0.f, 0.f, 0.f};
            if (dst < n) {
                int dgf = deg[dst];
                int dg = dgf < 64 ? dgf : 64;
                int dgp = (dg + 7) & ~7;
                for (int ib = 0; ib < dgp; ib += 8) {
#pragma unroll
                    for (int u = 0; u < 2; u++) {
                        int i = r * 64 + ib + u * 4 + e4;
                        int s = colL[i];
                        float4 w4 = ewL4[i];
                        unsigned xv = xbu[(size_t)s * 16 + cp];
                        float lo, hi;
                        unpack2(xv, lo, hi);
                        acc0[0] += lo * w4.x; acc1[0] += hi * w4.x;
                        acc0[1] += lo * w4.y; acc1[1] += hi * w4.y;
                        acc0[2] += lo * w4.z; acc1[2] += hi * w4.z;
                        acc0[3] += lo * w4.w; acc1[3] += hi * w4.w;
                        wsv[0] += w4.x; wsv[1] += w4.y;
                        wsv[2] += w4.z; wsv[3] += w4.w;
                    }
                }
            }
            // cross-group fold (xor 16, 32): all lanes end with full sums
#pragma unroll
            for (int off = 16; off <= 32; off <<= 1) {
#pragma unroll
                for (int c = 0; c < 4; c++) {
                    acc0[c] += __shfl_xor(acc0[c], off);
                    acc1[c] += __shfl_xor(acc1[c], off);
                    wsv[c]  += __shfl_xor(wsv[c],  off);
                }
            }
            if (dst < n) {
                float a0s, a1s, wss;
                if (e4 == 0)      { a0s = acc0[0]; a1s = acc1[0]; wss = wsv[0]; }
                else if (e4 == 1) { a0s = acc0[1]; a1s = acc1[1]; wss = wsv[1]; }
                else if (e4 == 2) { a0s = acc0[2]; a1s = acc1[2]; wss = wsv[2]; }
                else              { a0s = acc0[3]; a1s = acc1[3]; wss = wsv[3]; }
                float inv = 1.0f / (wss + 1e-16f);
                unsigned short p0 = f2bf(a0s * inv), p1 = f2bf(a1s * inv);
                *(unsigned*)(agx + r * 136 + e4 * 32 + cp * 2) =
                    ((unsigned)p1 << 16) | p0;
            } else {
                *(unsigned*)(agx + r * 136 + e4 * 32 + cp * 2) = 0u;
            }
        }
    }
    __syncthreads();

    // ---- phase 2: per-head [16x32]@[32x64] MFMA -> relu -> xs ----
    if (w < 4) {
        int h = w;
        int mm = lane & 15, quad = lane >> 4;
        bf16x8 a = *((const bf16x8*)(agx + mm * 136 + h * 32 + quad * 8));
#pragma unroll
        for (int nt = 0; nt < 4; nt++) {
            bf16x8 bfr = *((const bf16x8*)(W1p + (h * 4 + nt) * 512 + lane * 8));
            floatx4 c = {0.f, 0.f, 0.f, 0.f};
            c = __builtin_amdgcn_mfma_f32_16x16x32_bf16(a, bfr, c, 0, 0, 0);
            int ch = h * 64 + nt * 16 + mm;
            float bb = b1[ch];
#pragma unroll
            for (int q = 0; q < 4; q++) {
                int node = quad * 4 + q;
                xs[node * 264 + ch] = f2bf(fmaxf(c[q] + bb, 0.f));
            }
        }
    }
    __syncthreads();

    // ---- phase 3: MFMA out1[16,256] @ W2p -> h2 + logits (waves 0-3) ----
    if (w < 4) {
        int m = lane & 15, quad = lane >> 4;
        floatx4 acc = {0.f, 0.f, 0.f, 0.f};
#pragma unroll
        for (int kt = 0; kt < 8; kt++) {
            bf16x8 a = *((const bf16x8*)(xs + m * 264 + kt * 32 + quad * 8));
            bf16x8 b = *((const bf16x8*)(W2p + (w * 8 + kt) * 512 + lane * 8));
            acc = __builtin_amdgcn_mfma_f32_16x16x32_bf16(a, b, acc, 0, 0, 0);
        }
        int colg = w * 16 + m;
        float a_s = asr[colg], a_d = adt[colg];
        float ps[4], pd[4];
#pragma unroll
        for (int q = 0; q < 4; q++) {
            int node = base + quad * 4 + q;
            if (node < n) h2b[(size_t)node * 64 + colg] = __float2bfloat16(acc[q]);
            ps[q] = acc[q] * a_s;
            pd[q] = acc[q] * a_d;
#pragma unroll
            for (int off = 1; off <= 8; off <<= 1) {
                ps[q] += __shfl_xor(ps[q], off);
                pd[q] += __shfl_xor(pd[q], off);
            }
            if (m == 0) {
                aps[w][quad * 4 + q] = ps[q];
                apd[w][quad * 4 + q] = pd[q];
            }
        }
    }
    __syncthreads();
    if (t < 16 && base + t < n) {
        als[base + t] = aps[0][t] + aps[1][t] + aps[2][t] + aps[3][t];
        ald[base + t] = apd[0][t] + apd[1][t] + apd[2][t] + apd[3][t];
        dinv[base + t] = rsqrtf(fmaxf((float)deg[base + t], 1.0f));
    }
}

// ---------------- FUSED: GAT2 aggregate + GCN transform via MFMA -----------
// Block-cooperative edge staging (16x64 slots), then per-wave LDS-fed loops.
__global__ __launch_bounds__(512) void gat2_agg_mfma_gcn(
        const unsigned short* __restrict__ h2b,
        const float* __restrict__ als2, const float* __restrict__ ald2,
        const int* __restrict__ deg, const int* __restrict__ col64,
        const float* __restrict__ b2,
        const unsigned short* __restrict__ Wgp,
        unsigned short* __restrict__ h3b, int n) {
    __shared__ unsigned short h2L[16 * 72];   // row stride 144B
    __shared__ float ewL2[1024];
    __shared__ int   colL2[1024];
    int t = threadIdx.x;
    int w = t >> 6, lane = t & 63;
    int base = blockIdx.x * 16;
    int eg = lane >> 3, cl = lane & 7;

    // ---- phase 0: cooperative edge staging ----
    for (int rep = 0; rep < 2; rep++) {
        int idx = t + 512 * rep;
        int r = idx >> 6, e = idx & 63;
        int dst = base + r;
        int s = 0; float wv = 0.f;
        if (dst < n) {
            int dgf = deg[dst];
            int dg = dgf < 64 ? dgf : 64;
            if (e < dg) {
                s = col64[(size_t)dst * 64 + e];
                wv = __expf(leaky(als2[s] + ald2[dst]));
            }
        }
        colL2[idx] = s;
        ewL2[idx] = wv;
    }
    __syncthreads();

    for (int rep = 0; rep < 2; rep++) {
        int r = w * 2 + rep;
        int dst = base + r;
        if (dst < n) {
            int dgf = deg[dst];
            int dg = dgf < 64 ? dgf : 64;
            float acc[8];
#pragma unroll
            for (int j = 0; j < 8; j++) acc[j] = 0.f;
            float wsum = 0.f;
            for (int ib = 0; ib < dg; ib += 16) {
                int i0 = r * 64 + ib + eg, i1 = r * 64 + ib + 8 + eg;
                int s0 = colL2[i0], s1 = colL2[i1];
                float w0 = ewL2[i0], w1 = ewL2[i1];
                uint4 hv0 = *((const uint4*)(h2b + (size_t)s0 * 64) + cl);
                uint4 hv1 = *((const uint4*)(h2b + (size_t)s1 * 64) + cl);
                wsum += w0 + w1;
                float l0, u0, l1, u1, l2, u2, l3, u3;
                unpack2(hv0.x, l0, u0); unpack2(hv0.y, l1, u1);
                unpack2(hv0.z, l2, u2); unpack2(hv0.w, l3, u3);
                acc[0] += l0 * w0; acc[1] += u0 * w0;
                acc[2] += l1 * w0; acc[3] += u1 * w0;
                acc[4] += l2 * w0; acc[5] += u2 * w0;
                acc[6] += l3 * w0; acc[7] += u3 * w0;
                unpack2(hv1.x, l0, u0); unpack2(hv1.y, l1, u1);
                unpack2(hv1.z, l2, u2); unpack2(hv1.w, l3, u3);
                acc[0] += l0 * w1; acc[1] += u0 * w1;
                acc[2] += l1 * w1; acc[3] += u1 * w1;
                acc[4] += l2 * w1; acc[5] += u2 * w1;
                acc[6] += l3 * w1; acc[7] += u3 * w1;
            }
#pragma unroll
            for (int off = 8; off <= 32; off <<= 1) {
                wsum += __shfl_xor(wsum, off);
#pragma unroll
                for (int j = 0; j < 8; j++) acc[j] += __shfl_xor(acc[j], off);
            }
            float inv = 1.0f / (wsum + 1e-16f);
            if (lane < 8) {
                const float* bb = b2 + cl * 8;
                unsigned short pk[8];
#pragma unroll
                for (int j = 0; j < 8; j++)
                    pk[j] = f2bf(fmaxf(acc[j] * inv + bb[j], 0.f));
                *((uint4*)(h2L + r * 72 + cl * 8)) = *(const uint4*)pk;
            }
        } else if (lane < 8) {
            unsigned short z[8] = {0, 0, 0, 0, 0, 0, 0, 0};
            *((uint4*)(h2L + r * 72 + cl * 8)) = *(const uint4*)z;
        }
    }
    __syncthreads();

    // phase 2: relu2[16,64] @ Wg[64,32] -> h3 bf16 (waves 0-1, 2 MFMAs each)
    if (w < 2) {
        int m = lane & 15, quad = lane >> 4;
        floatx4 acc = {0.f, 0.f, 0.f, 0.f};
#pragma unroll
        for (int kt = 0; kt < 2; kt++) {
            bf16x8 a = *((const bf16x8*)(h2L + m * 72 + kt * 32 + quad * 8));
            bf16x8 bfr = *((const bf16x8*)(Wgp + (w * 2 + kt) * 512 + lane * 8));
            acc = __builtin_amdgcn_mfma_f32_16x16x32_bf16(a, bfr, acc, 0, 0, 0);
        }
#pragma unroll
        for (int q = 0; q < 4; q++) {
            int node = base + quad * 4 + q;
            if (node < n) h3b[(size_t)node * 32 + w * 16 + m] = f2bf(acc[q]);
        }
    }
}

// 16 dsts/block (4 waves x 4 dsts): cooperative norm staging, LDS-fed gather,
// and a 16-row merged pooled flush.
__global__ void gcn_agg_pool(const unsigned short* __restrict__ h3b,
                             const float* __restrict__ dinv,
                             const int* __restrict__ deg, const int* __restrict__ col64,
                             const float* __restrict__ bg, const int* __restrict__ batch,
                             float* __restrict__ pooled, int n) {
    __shared__ float rowL[16][32];
    __shared__ int gL[16];
    __shared__ int   colL3[1024];
    __shared__ float nwL3[1024];
    int t = threadIdx.x;
    int w = t >> 6, lane = t & 63;
    int base = blockIdx.x * 16;

    // ---- phase 0: cooperative norm staging (1024 slots, 4 per thread) ----
    for (int rep = 0; rep < 4; rep++) {
        int idx = t + 256 * rep;
        int r = idx >> 6, e = idx & 63;
        int dst = base + r;
        int s = 0; float nw = 0.f;
        if (dst < n) {
            int dgf = deg[dst];
            int dg = dgf < 64 ? dgf : 64;
            if (e < dg) {
                s = col64[(size_t)dst * 64 + e];
                nw = dinv[s] * dinv[dst];
            }
        }
        colL3[idx] = s;
        nwL3[idx] = nw;
    }
    __syncthreads();

    int eg = lane >> 3, cl = lane & 7;
    for (int rep = 0; rep < 4; rep++) {
        int r = w * 4 + rep;
        int dst = base + r;
        if (dst < n) {
            int dgf = deg[dst];
            int dg = dgf < 64 ? dgf : 64;
            float4 acc = make_float4(0.f, 0.f, 0.f, 0.f);
            for (int ib = 0; ib < dg; ib += 16) {
                int i0 = r * 64 + ib + eg, i1 = r * 64 + ib + 8 + eg;
                int s0 = colL3[i0], s1 = colL3[i1];
                float n0 = nwL3[i0], n1 = nwL3[i1];
                uint2 hv0 = *((const uint2*)(h3b + (size_t)s0 * 32) + cl);
                uint2 hv1 = *((const uint2*)(h3b + (size_t)s1 * 32) + cl);
                float l0, u0, l1, u1;
                unpack2(hv0.x, l0, u0); unpack2(hv0.y, l1, u1);
                acc.x += l0 * n0; acc.y += u0 * n0;
                acc.z += l1 * n0; acc.w += u1 * n0;
                unpack2(hv1.x, l0, u0); unpack2(hv1.y, l1, u1);
                acc.x += l0 * n1; acc.y += u0 * n1;
                acc.z += l1 * n1; acc.w += u1 * n1;
            }
#pragma unroll
            for (int off = 8; off <= 32; off <<= 1) {
                acc.x += __shfl_xor(acc.x, off);
                acc.y += __shfl_xor(acc.y, off);
                acc.z += __shfl_xor(acc.z, off);
                acc.w += __shfl_xor(acc.w, off);
            }
            if (lane == 0) gL[r] = batch[dst];
            if (lane < 8) {
                float4 bb = ((const float4*)bg)[cl];
                float4 o;
                o.x = fmaxf(acc.x + bb.x, 0.f);
                o.y = fmaxf(acc.y + bb.y, 0.f);
                o.z = fmaxf(acc.z + bb.z, 0.f);
                o.w = fmaxf(acc.w + bb.w, 0.f);
                *((float4*)&rowL[r][cl * 4]) = o;
            }
        } else if (lane == 0) {
            gL[r] = -1;
        }
    }
    __syncthreads();
    if (t < 32) {
        float cur = 0.f; int curg = -1;
#pragma unroll
        for (int r = 0; r < 16; r++) {
            int g = gL[r];
            if (g < 0) continue;
            float v = rowL[r][t];
            if (g == curg) cur += v;
            else {
                if (curg >= 0) atomicAdd(&pooled[curg * 32 + t], cur);
                curg = g; cur = v;
            }
        }
        if (curg >= 0) atomicAdd(&pooled[curg * 32 + t], cur);
    }
}

// ---------------- head: pooled sums -> mean -> anomaly[64] + emb[64,64] ----
__device__ __forceinline__ int lbound(const int* __restrict__ b, int n, int key) {
    int lo = 0, hi = n;
    while (lo < hi) { int m = (lo + hi) >> 1; if (b[m] < key) lo = m + 1; else hi = m; }
    return lo;
}

__global__ void head_kernel(const float* __restrict__ pooled_s,
                            const int* __restrict__ batch, int n,
                            const float* __restrict__ A1, const float* __restrict__ ba1,
                            const float* __restrict__ A2, const float* __restrict__ ba2,
                            const float* __restrict__ A3, const float* __restrict__ ba3,
                            const float* __restrict__ Wemb, const float* __restrict__ bemb,
                            float* __restrict__ out) {
    __shared__ float P[64 * 32];
    __shared__ float Z1[64 * 32];
    __shared__ float Z2[64 * 16];
    __shared__ int cntL[64];
    int t = threadIdx.x;
    if (t < 64) cntL[t] = lbound(batch, n, t + 1) - lbound(batch, n, t);
    __syncthreads();
    for (int i = t; i < 64 * 32; i += 256) {
        int g = i >> 5;
        P[i] = pooled_s[i] / fmaxf((float)cntL[g], 1.0f);
    }
    __syncthreads();
    for (int i = t; i < 64 * 32; i += 256) {
        int g = i >> 5, c = i & 31;
        float a = ba1[c];
#pragma unroll
        for (int k = 0; k < 32; k++) a += P[g * 32 + k] * A1[k * 32 + c];
        Z1[i] = a > 0.f ? a : 0.f;
    }
    __syncthreads();
    for (int i = t; i < 64 * 16; i += 256) {
        int g = i >> 4, c = i & 15;
        float a = ba2[c];
#pragma unroll
        for (int k = 0; k < 32; k++) a += Z1[g * 32 + k] * A2[k * 16 + c];
        Z2[i] = a > 0.f ? a : 0.f;
    }
    __syncthreads();
    for (int g = t; g < 64; g += 256) {
        float a = ba3[0];
#pragma unroll
        for (int k = 0; k < 16; k++) a += Z2[g * 16 + k] * A3[k];
        out[g] = 1.0f / (1.0f + expf(-a));
    }
    for (int i = t; i < 64 * 64; i += 256) {
        int g = i >> 6, c = i & 63;
        float a = bemb[c];
#pragma unroll
        for (int k = 0; k < 32; k++) a += P[g * 32 + k] * Wemb[k * 64 + c];
        out[64 + i] = tanhf(a);
    }
}

extern "C" void kernel_launch(void* const* d_in, const int* in_sizes, int n_in,
                              void* d_out, int out_size, void* d_ws, size_t ws_size,
                              hipStream_t stream) {
    const float* x    = (const float*)d_in[0];
    const int*   ei   = (const int*)d_in[1];
    const int*   batch= (const int*)d_in[2];
    const float* W1   = (const float*)d_in[3];
    const float* as1  = (const float*)d_in[4];
    const float* ad1  = (const float*)d_in[5];
    const float* b1   = (const float*)d_in[6];
    const float* W2   = (const float*)d_in[7];
    const float* as2  = (const float*)d_in[8];
    const float* ad2  = (const float*)d_in[9];
    const float* b2   = (const float*)d_in[10];
    const float* Wg   = (const float*)d_in[11];
    const float* bg   = (const float*)d_in[12];
    const float* A1   = (const float*)d_in[13];
    const float* ba1  = (const float*)d_in[14];
    const float* A2   = (const float*)d_in[15];
    const float* ba2  = (const float*)d_in[16];
    const float* A3   = (const float*)d_in[17];
    const float* ba3  = (const float*)d_in[18];
    const float* Wemb = (const float*)d_in[19];
    const float* bemb = (const float*)d_in[20];
    float* out = (float*)d_out;

    const int N = in_sizes[0] / 32;
    const int E = in_sizes[1] / 2;
    const int ET = E + N;

    char* base = (char*)d_ws;
    size_t off = 0;
    auto take = [&](size_t bytes) -> char* {
        char* p = base + off;
        off = (off + bytes + 255) & ~(size_t)255;
        return p;
    };
    // ---- zeroed-by-memset prefix: deg, pooled ----
    int*   deg    = (int*)take((size_t)N * 4);
    float* pooled = (float*)take(64 * 32 * 4);
    size_t zspan  = off;
    // ---- rest ----
    int*   col64  = (int*)take((size_t)N * 64 * 4);   // ELL: 64 slots/dst
    float* dinv   = (float*)take((size_t)N * 4);
    float* als1   = (float*)take((size_t)N * 16);     // node-major [n][4]
    float* ald1   = (float*)take((size_t)N * 16);
    unsigned short* W2p = (unsigned short*)take(32 * 512 * 2);
    unsigned short* W1p = (unsigned short*)take(16 * 512 * 2);
    unsigned short* Wgp = (unsigned short*)take(4 * 512 * 2);
    unsigned* xbu = (unsigned*)take((size_t)N * 64);  // bf16 x rows
    __hip_bfloat16* h2b = (__hip_bfloat16*)take((size_t)N * 128);
    float* als2 = (float*)take((size_t)N * 4);
    float* ald2 = (float*)take((size_t)N * 4);
    unsigned short* h3b = (unsigned short*)take((size_t)N * 64);

    int gN16 = (N + 15) / 16;
    int gT = (N + 63) / 64;
    int gF = (ET + 255) / 256;
    int gPre = gT + gF + 1;

    hipMemsetAsync(d_ws, 0, zspan, stream);

    prelude<<<gPre, 256, 0, stream>>>(x, W1, as1, ad1, W2, Wg, ei, xbu,
                                      als1, ald1, W2p, W1p, Wgp, deg, col64,
                                      N, E, gT, gF);
    gat1_agg_mfma<<<gN16, 512, 0, stream>>>(xbu, als1, ald1, deg, col64, b1,
                                            W1p, W2p, as2, ad2,
                                            h2b, als2, ald2, dinv, N);
    gat2_agg_mfma_gcn<<<gN16, 512, 0, stream>>>((const unsigned short*)h2b,
                                                als2, ald2, deg, col64, b2,
                                                Wgp, h3b, N);
    gcn_agg_pool<<<gN16, 256, 0, stream>>>(h3b, dinv, deg, col64, bg, batch,
                                           pooled, N);
    head_kernel<<<1, 256, 0, stream>>>(pooled, batch, N, A1, ba1, A2, ba2, A3, ba3,
                                       Wemb, bemb, out);
}

// Round 13
// 177.666 us; speedup vs baseline: 1.0471x; 1.0471x over previous
//
#include <hip/hip_runtime.h>
#include <hip/hip_bf16.h>

#define NEG 0.2f

typedef short bf16x8 __attribute__((ext_vector_type(8)));
typedef float floatx4 __attribute__((ext_vector_type(4)));

__device__ __forceinline__ float leaky(float v) { return v > 0.f ? v : NEG * v; }

__device__ __forceinline__ void unpack2(unsigned w, float& lo, float& hi) {
    union { unsigned u; float f; } a, b;
    a.u = w << 16;
    b.u = w & 0xffff0000u;
    lo = a.f; hi = b.f;
}

__device__ __forceinline__ unsigned short f2bf(float f) {
    union { float f; unsigned u; } v; v.f = f;
    unsigned r = v.u + 0x7fff + ((v.u >> 16) & 1);
    return (unsigned short)(r >> 16);
}

// ---------------- prelude: logits + x->bf16 + ELL edge fill + W packs ------
__global__ void prelude(const float* __restrict__ x, const float* __restrict__ W1,
                        const float* __restrict__ as1, const float* __restrict__ ad1,
                        const float* __restrict__ W2, const float* __restrict__ Wg,
                        const int* __restrict__ ei,
                        unsigned* __restrict__ xbu,          // [n][16] packed bf16x2
                        float* __restrict__ als1, float* __restrict__ ald1,
                        unsigned short* __restrict__ W2p,
                        unsigned short* __restrict__ W1p,
                        unsigned short* __restrict__ Wgp,
                        int* __restrict__ deg, int* __restrict__ col64,
                        int n, int E, int nTB, int nFB) {
    __shared__ float xr[64][36];      // stride 36: 16B-aligned float4 rows
    __shared__ float WaS[128];        // [j*4+h] = sum_c W1[j][h*64+c]*a_src[h][c]
    __shared__ float WaD[128];
    int b = blockIdx.x;
    int t = threadIdx.x;

    if (b >= nTB) {
        int fb = b - nTB;
        if (fb < nFB) {
            int i = fb * 256 + t;
            int tot = E + n;
            if (i < tot) {
                int src, dst;
                if (i < E) { src = ei[i]; dst = ei[E + i]; }
                else { src = i - E; dst = i - E; }
                int slot = atomicAdd(&deg[dst], 1);
                if (slot < 64) col64[(size_t)dst * 64 + slot] = src;
            }
        } else {
            // pack W2 [256,64] -> bf16 MFMA B fragments (K=32 tiles x 8)
            for (int idx = t; idx < 32 * 64; idx += 256) {
                int frag = idx >> 6, lane = idx & 63;
                int ct = frag >> 3, kt = frag & 7;
                int nn = ct * 16 + (lane & 15);
                int kb = kt * 32 + (lane >> 4) * 8;
#pragma unroll
                for (int j = 0; j < 8; j++)
                    W2p[frag * 512 + lane * 8 + j] = f2bf(W2[(kb + j) * 64 + nn]);
            }
            // pack W1 [32,256] -> per-head B fragments: frag = h*4+nt
            for (int idx = t; idx < 16 * 512; idx += 256) {
                int frag = idx >> 9;
                int h = frag >> 2, nt = frag & 3;
                int pos = idx & 511;
                int lane = pos >> 3, j = pos & 7;
                int coln = lane & 15, quad = lane >> 4;
                int k = quad * 8 + j;
                W1p[idx] = f2bf(W1[k * 256 + h * 64 + nt * 16 + coln]);
            }
            // pack Wg [64,32] -> B fragments: frag = nt*2+kt (nt,kt in 0..1)
            for (int idx = t; idx < 4 * 512; idx += 256) {
                int frag = idx >> 9;
                int nt = frag >> 1, kt = frag & 1;
                int pos = idx & 511;
                int lane = pos >> 3, j = pos & 7;
                int coln = lane & 15, quad = lane >> 4;
                int k = kt * 32 + quad * 8 + j;
                Wgp[idx] = f2bf(Wg[k * 32 + nt * 16 + coln]);
            }
        }
        return;
    }

    // ---- 64 nodes: stage x, rank-1 logit tables, logits, xb bf16 ----
    int base = b * 64;
    for (int rep = 0; rep < 2; rep++) {
        int s = t + 256 * rep;            // float4 slot 0..511
        int node = s >> 3, quad = s & 7;
        float4 v = make_float4(0.f, 0.f, 0.f, 0.f);
        if (base + node < n) v = ((const float4*)(x + (size_t)base * 32))[s];
        *((float4*)(&xr[node][quad * 4])) = v;
    }
    {
        int j = (t & 127) >> 2, h = t & 3;
        const float* av = (t < 128) ? as1 : ad1;
        float s_ = 0.f;
#pragma unroll 8
        for (int c = 0; c < 64; c++) s_ += W1[j * 256 + h * 64 + c] * av[h * 64 + c];
        if (t < 128) WaS[t] = s_; else WaD[t - 128] = s_;
    }
    __syncthreads();

    // logits: 64 nodes x 4 heads x {src,dst} = 512 32-dots
    for (int rep = 0; rep < 2; rep++) {
        int q = t + 256 * rep;
        int node = q >> 3, r = q & 7, h = r >> 1, sd = r & 1;
        int gnode = base + node;
        if (gnode < n) {
            const float* cf = sd ? WaD : WaS;
            float d_ = 0.f;
#pragma unroll
            for (int j = 0; j < 32; j++) d_ += xr[node][j] * cf[j * 4 + h];
            if (sd == 0) als1[(size_t)gnode * 4 + h] = d_;
            else         ald1[(size_t)gnode * 4 + h] = d_;
        }
    }
    // xb: bf16 x rows (the gather target - 1.25 MB, L2-resident)
    for (int rep = 0; rep < 4; rep++) {
        int i = t + 256 * rep;            // 0..1023 = 64 nodes x 16 pairs
        int node = i >> 4, cp = i & 15;
        int gnode = base + node;
        if (gnode < n) {
            unsigned short u0 = f2bf(xr[node][cp * 2]);
            unsigned short u1 = f2bf(xr[node][cp * 2 + 1]);
            xbu[(size_t)gnode * 16 + cp] = ((unsigned)u1 << 16) | u0;
        }
    }
}

// ---------------- FUSED: GAT1 x-space aggregate + W1 MFMA + W2 MFMA --------
// Phase 1 uses a PARALLEL EDGE-WEIGHT PROLOGUE: all 64 lanes each handle
// one edge (col load + als1 gather + 4 exps) and stage {col, w4} in per-wave
// LDS. The main loop then has ONE global dependency per edge (xbu gather),
// runs branch-free over the padded count, and unrolls 8-deep.
// (R11 block-coop staging and R12 4-edge relayout both measured neutral or
// negative vs this layout - R10 config is the session best.)
__global__ __launch_bounds__(512) void gat1_agg_mfma(
        const unsigned* __restrict__ xbu,
        const float* __restrict__ als1, const float* __restrict__ ald1,
        const int* __restrict__ deg, const int* __restrict__ col64,
        const float* __restrict__ b1,
        const unsigned short* __restrict__ W1p,
        const unsigned short* __restrict__ W2p,
        const float* __restrict__ asr, const float* __restrict__ adt,
        __hip_bfloat16* __restrict__ h2b,
        float* __restrict__ als, float* __restrict__ ald,
        float* __restrict__ dinv, int n) {
    __shared__ unsigned short xs[16 * 264];
    __shared__ unsigned short agx[16 * 136];   // [node][h*32+ch] bf16
    __shared__ float aps[4][16];
    __shared__ float apd[4][16];
    __shared__ float ewL[8 * 64 * 4];          // per-wave edge weights (float4/edge)
    __shared__ int   colL[8 * 64];             // per-wave edge sources
    int t = threadIdx.x;              // 512 = 8 waves
    int w = t >> 6, lane = t & 63;
    int base = blockIdx.x * 16;

    // ---- phase 1: x-space aggregation, 2 dsts per wave ----
    {
        int h = lane >> 4, cp = lane & 15;
        for (int rep = 0; rep < 2; rep++) {
            int r = w * 2 + rep;
            int dst = base + r;
            if (dst < n) {
                int dgf = deg[dst];
                int dg = dgf < 64 ? dgf : 64;
                const int* cb = col64 + (size_t)dst * 64;
                // prologue: lane e computes edge e's 4 head-weights in parallel
                {
                    bool v = lane < dg;
                    int s = v ? cb[lane] : 0;
                    float4 as4 = ((const float4*)als1)[s];
                    float4 ad4 = ((const float4*)ald1)[dst];
                    float4 w4;
                    w4.x = v ? __expf(leaky(as4.x + ad4.x)) : 0.f;
                    w4.y = v ? __expf(leaky(as4.y + ad4.y)) : 0.f;
                    w4.z = v ? __expf(leaky(as4.z + ad4.z)) : 0.f;
                    w4.w = v ? __expf(leaky(as4.w + ad4.w)) : 0.f;
                    colL[w * 64 + lane] = s;
                    *((float4*)&ewL[(w * 64 + lane) * 4]) = w4;
                }
                // main loop: branch-free, 8 gathers in flight, LDS-fed weights
                int dgp = (dg + 7) & ~7;
                float a0 = 0.f, a1 = 0.f, ws = 0.f;
                for (int ib = 0; ib < dgp; ib += 8) {
                    int ss[8]; float wv[8];
#pragma unroll
                    for (int u = 0; u < 8; u++) {
                        int i = ib + u;
                        ss[u] = colL[w * 64 + i];
                        wv[u] = ewL[(w * 64 + i) * 4 + h];
                    }
                    float lo[8], hi[8];
#pragma unroll
                    for (int u = 0; u < 8; u++) {
                        unsigned xv = xbu[(size_t)ss[u] * 16 + cp];
                        unpack2(xv, lo[u], hi[u]);
                    }
#pragma unroll
                    for (int u = 0; u < 8; u++) {
                        a0 += lo[u] * wv[u];
                        a1 += hi[u] * wv[u];
                        ws += wv[u];
                    }
                }
                float inv = 1.0f / (ws + 1e-16f);
                unsigned short p0 = f2bf(a0 * inv), p1 = f2bf(a1 * inv);
                *(unsigned*)(agx + r * 136 + h * 32 + cp * 2) =
                    ((unsigned)p1 << 16) | p0;
            } else {
                *(unsigned*)(agx + r * 136 + h * 32 + cp * 2) = 0u;
            }
        }
    }
    __syncthreads();

    // ---- phase 2: per-head [16x32]@[32x64] MFMA -> relu -> xs ----
    if (w < 4) {
        int h = w;
        int mm = lane & 15, quad = lane >> 4;
        bf16x8 a = *((const bf16x8*)(agx + mm * 136 + h * 32 + quad * 8));
#pragma unroll
        for (int nt = 0; nt < 4; nt++) {
            bf16x8 bfr = *((const bf16x8*)(W1p + (h * 4 + nt) * 512 + lane * 8));
            floatx4 c = {0.f, 0.f, 0.f, 0.f};
            c = __builtin_amdgcn_mfma_f32_16x16x32_bf16(a, bfr, c, 0, 0, 0);
            int ch = h * 64 + nt * 16 + mm;
            float bb = b1[ch];
#pragma unroll
            for (int q = 0; q < 4; q++) {
                int node = quad * 4 + q;
                xs[node * 264 + ch] = f2bf(fmaxf(c[q] + bb, 0.f));
            }
        }
    }
    __syncthreads();

    // ---- phase 3: MFMA out1[16,256] @ W2p -> h2 + logits (waves 0-3) ----
    if (w < 4) {
        int m = lane & 15, quad = lane >> 4;
        floatx4 acc = {0.f, 0.f, 0.f, 0.f};
#pragma unroll
        for (int kt = 0; kt < 8; kt++) {
            bf16x8 a = *((const bf16x8*)(xs + m * 264 + kt * 32 + quad * 8));
            bf16x8 b = *((const bf16x8*)(W2p + (w * 8 + kt) * 512 + lane * 8));
            acc = __builtin_amdgcn_mfma_f32_16x16x32_bf16(a, b, acc, 0, 0, 0);
        }
        int colg = w * 16 + m;
        float a_s = asr[colg], a_d = adt[colg];
        float ps[4], pd[4];
#pragma unroll
        for (int q = 0; q < 4; q++) {
            int node = base + quad * 4 + q;
            if (node < n) h2b[(size_t)node * 64 + colg] = __float2bfloat16(acc[q]);
            ps[q] = acc[q] * a_s;
            pd[q] = acc[q] * a_d;
#pragma unroll
            for (int off = 1; off <= 8; off <<= 1) {
                ps[q] += __shfl_xor(ps[q], off);
                pd[q] += __shfl_xor(pd[q], off);
            }
            if (m == 0) {
                aps[w][quad * 4 + q] = ps[q];
                apd[w][quad * 4 + q] = pd[q];
            }
        }
    }
    __syncthreads();
    if (t < 16 && base + t < n) {
        als[base + t] = aps[0][t] + aps[1][t] + aps[2][t] + aps[3][t];
        ald[base + t] = apd[0][t] + apd[1][t] + apd[2][t] + apd[3][t];
        dinv[base + t] = rsqrtf(fmaxf((float)deg[base + t], 1.0f));
    }
}

// ---------------- FUSED: GAT2 aggregate + GCN transform via MFMA -----------
// Parallel edge-weight prologue: lane e computes exp weight for edge e,
// stages {col, w} in LDS; main loop branch-free with only the h2b gather.
__global__ __launch_bounds__(512) void gat2_agg_mfma_gcn(
        const unsigned short* __restrict__ h2b,
        const float* __restrict__ als2, const float* __restrict__ ald2,
        const int* __restrict__ deg, const int* __restrict__ col64,
        const float* __restrict__ b2,
        const unsigned short* __restrict__ Wgp,
        unsigned short* __restrict__ h3b, int n) {
    __shared__ unsigned short h2L[16 * 72];   // row stride 144B
    __shared__ float ewL2[8 * 64];
    __shared__ int   colL2[8 * 64];
    int t = threadIdx.x;
    int w = t >> 6, lane = t & 63;
    int base = blockIdx.x * 16;
    int eg = lane >> 3, cl = lane & 7;

    for (int rep = 0; rep < 2; rep++) {
        int r = w * 2 + rep;
        int dst = base + r;
        if (dst < n) {
            int dgf = deg[dst];
            int dg = dgf < 64 ? dgf : 64;
            const int* cb = col64 + (size_t)dst * 64;
            float a_d = ald2[dst];
            // prologue: lane e -> edge e weight
            {
                bool v = lane < dg;
                int s = v ? cb[lane] : 0;
                colL2[w * 64 + lane] = s;
                ewL2[w * 64 + lane] = v ? __expf(leaky(als2[s] + a_d)) : 0.f;
            }
            float acc[8];
#pragma unroll
            for (int j = 0; j < 8; j++) acc[j] = 0.f;
            float wsum = 0.f;
            for (int ib = 0; ib < dg; ib += 16) {
                int i0 = ib + eg, i1 = ib + 8 + eg;
                int s0 = colL2[w * 64 + i0], s1 = colL2[w * 64 + i1];
                float w0 = ewL2[w * 64 + i0], w1 = ewL2[w * 64 + i1];
                uint4 hv0 = *((const uint4*)(h2b + (size_t)s0 * 64) + cl);
                uint4 hv1 = *((const uint4*)(h2b + (size_t)s1 * 64) + cl);
                wsum += w0 + w1;
                float l0, u0, l1, u1, l2, u2, l3, u3;
                unpack2(hv0.x, l0, u0); unpack2(hv0.y, l1, u1);
                unpack2(hv0.z, l2, u2); unpack2(hv0.w, l3, u3);
                acc[0] += l0 * w0; acc[1] += u0 * w0;
                acc[2] += l1 * w0; acc[3] += u1 * w0;
                acc[4] += l2 * w0; acc[5] += u2 * w0;
                acc[6] += l3 * w0; acc[7] += u3 * w0;
                unpack2(hv1.x, l0, u0); unpack2(hv1.y, l1, u1);
                unpack2(hv1.z, l2, u2); unpack2(hv1.w, l3, u3);
                acc[0] += l0 * w1; acc[1] += u0 * w1;
                acc[2] += l1 * w1; acc[3] += u1 * w1;
                acc[4] += l2 * w1; acc[5] += u2 * w1;
                acc[6] += l3 * w1; acc[7] += u3 * w1;
            }
#pragma unroll
            for (int off = 8; off <= 32; off <<= 1) {
                wsum += __shfl_xor(wsum, off);
#pragma unroll
                for (int j = 0; j < 8; j++) acc[j] += __shfl_xor(acc[j], off);
            }
            float inv = 1.0f / (wsum + 1e-16f);
            if (lane < 8) {
                const float* bb = b2 + cl * 8;
                unsigned short pk[8];
#pragma unroll
                for (int j = 0; j < 8; j++)
                    pk[j] = f2bf(fmaxf(acc[j] * inv + bb[j], 0.f));
                *((uint4*)(h2L + r * 72 + cl * 8)) = *(const uint4*)pk;
            }
        } else if (lane < 8) {
            unsigned short z[8] = {0, 0, 0, 0, 0, 0, 0, 0};
            *((uint4*)(h2L + r * 72 + cl * 8)) = *(const uint4*)z;
        }
    }
    __syncthreads();

    // phase 2: relu2[16,64] @ Wg[64,32] -> h3 bf16 (waves 0-1, 2 MFMAs each)
    if (w < 2) {
        int m = lane & 15, quad = lane >> 4;
        floatx4 acc = {0.f, 0.f, 0.f, 0.f};
#pragma unroll
        for (int kt = 0; kt < 2; kt++) {
            bf16x8 a = *((const bf16x8*)(h2L + m * 72 + kt * 32 + quad * 8));
            bf16x8 bfr = *((const bf16x8*)(Wgp + (w * 2 + kt) * 512 + lane * 8));
            acc = __builtin_amdgcn_mfma_f32_16x16x32_bf16(a, bfr, acc, 0, 0, 0);
        }
#pragma unroll
        for (int q = 0; q < 4; q++) {
            int node = base + quad * 4 + q;
            if (node < n) h3b[(size_t)node * 32 + w * 16 + m] = f2bf(acc[q]);
        }
    }
}

// wave per dst; GCN aggregate (bf16 h3, ELL edges) FUSED with mean-pool
// accumulation. Parallel norm prologue (col + dinv product staged in LDS).
__global__ void gcn_agg_pool(const unsigned short* __restrict__ h3b,
                             const float* __restrict__ dinv,
                             const int* __restrict__ deg, const int* __restrict__ col64,
                             const float* __restrict__ bg, const int* __restrict__ batch,
                             float* __restrict__ pooled, int n) {
    __shared__ float rowL[4][32];
    __shared__ int gL[4];
    __shared__ int   colL3[4 * 64];
    __shared__ float nwL3[4 * 64];
    int t = threadIdx.x;
    int w = t >> 6, lane = t & 63;
    int dst = blockIdx.x * 4 + w;
    bool act = dst < n;
    if (act) {
        int dgf = deg[dst];
        int dg = dgf < 64 ? dgf : 64;
        const int* cb = col64 + (size_t)dst * 64;
        float dv = dinv[dst];
        // prologue: lane e -> edge e norm
        {
            bool v = lane < dg;
            int s = v ? cb[lane] : 0;
            colL3[w * 64 + lane] = s;
            nwL3[w * 64 + lane] = v ? dinv[s] * dv : 0.f;
        }
        int eg = lane >> 3;
        int cl = lane & 7;
        float4 acc = make_float4(0.f, 0.f, 0.f, 0.f);
        for (int ib = 0; ib < dg; ib += 16) {
            int i0 = ib + eg, i1 = ib + 8 + eg;
            int s0 = colL3[w * 64 + i0], s1 = colL3[w * 64 + i1];
            float n0 = nwL3[w * 64 + i0], n1 = nwL3[w * 64 + i1];
            uint2 hv0 = *((const uint2*)(h3b + (size_t)s0 * 32) + cl);
            uint2 hv1 = *((const uint2*)(h3b + (size_t)s1 * 32) + cl);
            float l0, u0, l1, u1;
            unpack2(hv0.x, l0, u0); unpack2(hv0.y, l1, u1);
            acc.x += l0 * n0; acc.y += u0 * n0;
            acc.z += l1 * n0; acc.w += u1 * n0;
            unpack2(hv1.x, l0, u0); unpack2(hv1.y, l1, u1);
            acc.x += l0 * n1; acc.y += u0 * n1;
            acc.z += l1 * n1; acc.w += u1 * n1;
        }
#pragma unroll
        for (int off = 8; off <= 32; off <<= 1) {
            acc.x += __shfl_xor(acc.x, off);
            acc.y += __shfl_xor(acc.y, off);
            acc.z += __shfl_xor(acc.z, off);
            acc.w += __shfl_xor(acc.w, off);
        }
        if (lane == 0) gL[w] = batch[dst];
        if (lane < 8) {
            float4 bb = ((const float4*)bg)[cl];
            float4 o;
            o.x = fmaxf(acc.x + bb.x, 0.f);
            o.y = fmaxf(acc.y + bb.y, 0.f);
            o.z = fmaxf(acc.z + bb.z, 0.f);
            o.w = fmaxf(acc.w + bb.w, 0.f);
            *((float4*)&rowL[w][cl * 4]) = o;
        }
    } else if (lane == 0) {
        gL[w] = -1;
    }
    __syncthreads();
    if (t < 32) {
        float cur = 0.f; int curg = -1;
#pragma unroll
        for (int r = 0; r < 4; r++) {
            int g = gL[r];
            if (g < 0) continue;
            float v = rowL[r][t];
            if (g == curg) cur += v;
            else {
                if (curg >= 0) atomicAdd(&pooled[curg * 32 + t], cur);
                curg = g; cur = v;
            }
        }
        if (curg >= 0) atomicAdd(&pooled[curg * 32 + t], cur);
    }
}

// ---------------- head: pooled sums -> mean -> anomaly[64] + emb[64,64] ----
__device__ __forceinline__ int lbound(const int* __restrict__ b, int n, int key) {
    int lo = 0, hi = n;
    while (lo < hi) { int m = (lo + hi) >> 1; if (b[m] < key) lo = m + 1; else hi = m; }
    return lo;
}

__global__ void head_kernel(const float* __restrict__ pooled_s,
                            const int* __restrict__ batch, int n,
                            const float* __restrict__ A1, const float* __restrict__ ba1,
                            const float* __restrict__ A2, const float* __restrict__ ba2,
                            const float* __restrict__ A3, const float* __restrict__ ba3,
                            const float* __restrict__ Wemb, const float* __restrict__ bemb,
                            float* __restrict__ out) {
    __shared__ float P[64 * 32];
    __shared__ float Z1[64 * 32];
    __shared__ float Z2[64 * 16];
    __shared__ int cntL[64];
    int t = threadIdx.x;
    if (t < 64) cntL[t] = lbound(batch, n, t + 1) - lbound(batch, n, t);
    __syncthreads();
    for (int i = t; i < 64 * 32; i += 256) {
        int g = i >> 5;
        P[i] = pooled_s[i] / fmaxf((float)cntL[g], 1.0f);
    }
    __syncthreads();
    for (int i = t; i < 64 * 32; i += 256) {
        int g = i >> 5, c = i & 31;
        float a = ba1[c];
#pragma unroll
        for (int k = 0; k < 32; k++) a += P[g * 32 + k] * A1[k * 32 + c];
        Z1[i] = a > 0.f ? a : 0.f;
    }
    __syncthreads();
    for (int i = t; i < 64 * 16; i += 256) {
        int g = i >> 4, c = i & 15;
        float a = ba2[c];
#pragma unroll
        for (int k = 0; k < 32; k++) a += Z1[g * 32 + k] * A2[k * 16 + c];
        Z2[i] = a > 0.f ? a : 0.f;
    }
    __syncthreads();
    for (int g = t; g < 64; g += 256) {
        float a = ba3[0];
#pragma unroll
        for (int k = 0; k < 16; k++) a += Z2[g * 16 + k] * A3[k];
        out[g] = 1.0f / (1.0f + expf(-a));
    }
    for (int i = t; i < 64 * 64; i += 256) {
        int g = i >> 6, c = i & 63;
        float a = bemb[c];
#pragma unroll
        for (int k = 0; k < 32; k++) a += P[g * 32 + k] * Wemb[k * 64 + c];
        out[64 + i] = tanhf(a);
    }
}

extern "C" void kernel_launch(void* const* d_in, const int* in_sizes, int n_in,
                              void* d_out, int out_size, void* d_ws, size_t ws_size,
                              hipStream_t stream) {
    const float* x    = (const float*)d_in[0];
    const int*   ei   = (const int*)d_in[1];
    const int*   batch= (const int*)d_in[2];
    const float* W1   = (const float*)d_in[3];
    const float* as1  = (const float*)d_in[4];
    const float* ad1  = (const float*)d_in[5];
    const float* b1   = (const float*)d_in[6];
    const float* W2   = (const float*)d_in[7];
    const float* as2  = (const float*)d_in[8];
    const float* ad2  = (const float*)d_in[9];
    const float* b2   = (const float*)d_in[10];
    const float* Wg   = (const float*)d_in[11];
    const float* bg   = (const float*)d_in[12];
    const float* A1   = (const float*)d_in[13];
    const float* ba1  = (const float*)d_in[14];
    const float* A2   = (const float*)d_in[15];
    const float* ba2  = (const float*)d_in[16];
    const float* A3   = (const float*)d_in[17];
    const float* ba3  = (const float*)d_in[18];
    const float* Wemb = (const float*)d_in[19];
    const float* bemb = (const float*)d_in[20];
    float* out = (float*)d_out;

    const int N = in_sizes[0] / 32;
    const int E = in_sizes[1] / 2;
    const int ET = E + N;

    char* base = (char*)d_ws;
    size_t off = 0;
    auto take = [&](size_t bytes) -> char* {
        char* p = base + off;
        off = (off + bytes + 255) & ~(size_t)255;
        return p;
    };
    // ---- zeroed-by-memset prefix: deg, pooled ----
    int*   deg    = (int*)take((size_t)N * 4);
    float* pooled = (float*)take(64 * 32 * 4);
    size_t zspan  = off;
    // ---- rest ----
    int*   col64  = (int*)take((size_t)N * 64 * 4);   // ELL: 64 slots/dst
    float* dinv   = (float*)take((size_t)N * 4);
    float* als1   = (float*)take((size_t)N * 16);     // node-major [n][4]
    float* ald1   = (float*)take((size_t)N * 16);
    unsigned short* W2p = (unsigned short*)take(32 * 512 * 2);
    unsigned short* W1p = (unsigned short*)take(16 * 512 * 2);
    unsigned short* Wgp = (unsigned short*)take(4 * 512 * 2);
    unsigned* xbu = (unsigned*)take((size_t)N * 64);  // bf16 x rows
    __hip_bfloat16* h2b = (__hip_bfloat16*)take((size_t)N * 128);
    float* als2 = (float*)take((size_t)N * 4);
    float* ald2 = (float*)take((size_t)N * 4);
    unsigned short* h3b = (unsigned short*)take((size_t)N * 64);

    int gN4 = (N + 3) / 4;
    int gN16 = (N + 15) / 16;
    int gT = (N + 63) / 64;
    int gF = (ET + 255) / 256;
    int gPre = gT + gF + 1;

    hipMemsetAsync(d_ws, 0, zspan, stream);

    prelude<<<gPre, 256, 0, stream>>>(x, W1, as1, ad1, W2, Wg, ei, xbu,
                                      als1, ald1, W2p, W1p, Wgp, deg, col64,
                                      N, E, gT, gF);
    gat1_agg_mfma<<<gN16, 512, 0, stream>>>(xbu, als1, ald1, deg, col64, b1,
                                            W1p, W2p, as2, ad2,
                                            h2b, als2, ald2, dinv, N);
    gat2_agg_mfma_gcn<<<gN16, 512, 0, stream>>>((const unsigned short*)h2b,
                                                als2, ald2, deg, col64, b2,
                                                Wgp, h3b, N);
    gcn_agg_pool<<<gN4, 256, 0, stream>>>(h3b, dinv, deg, col64, bg, batch,
                                          pooled, N);
    head_kernel<<<1, 256, 0, stream>>>(pooled, batch, N, A1, ba1, A2, ba2, A3, ba3,
                                       Wemb, bemb, out);
}